// Round 6
// baseline (42.050 us; speedup 1.0000x reference)
//
#include <hip/hip_runtime.h>
#include <math.h>

#define B_     32
#define S_     1024
#define H2_    1024
#define TOPIC_ 256

__device__ __forceinline__ float fast_tanh(float x) {
    // tanh(x) = 1 - 2/(exp(2x)+1); saturates to +-1 at extremes.
    float e = __expf(2.0f * x);
    return 1.0f - 2.0f / (e + 1.0f);
}

// Kernel 1: combined[b][h] = sum_k s[b][k]*W_s[k][h] + sum_j hz[b][j]*W_z[j][h] + b_c[h]
// grid = (H2/32, B) = (32, 32), block = 256 (8 k-chunks x 32 h)
__global__ __launch_bounds__(256) void combined_kernel(
    const float* __restrict__ s,    // [B, H2]
    const float* __restrict__ hz,   // [B, TOPIC]
    const float* __restrict__ W_s,  // [H2, H2]  (in, out)
    const float* __restrict__ W_z,  // [TOPIC, H2]
    const float* __restrict__ b_c,  // [H2]
    float* __restrict__ combined)   // [B, H2]
{
    const int b  = blockIdx.y;
    const int hl = threadIdx.x & 31;
    const int h  = blockIdx.x * 32 + hl;
    const int kc = threadIdx.x >> 5;   // 0..7

    __shared__ float sx[H2_];
    __shared__ float zx[TOPIC_];
    for (int i = threadIdx.x; i < H2_; i += 256)    sx[i] = s[b * H2_ + i];
    for (int i = threadIdx.x; i < TOPIC_; i += 256) zx[i] = hz[b * TOPIC_ + i];
    __syncthreads();

    // 4 independent accumulators -> loads pipeline instead of serializing
    float a0 = 0.f, a1 = 0.f, a2 = 0.f, a3 = 0.f;
    {
        const int k0 = kc * 128;                       // 1024 / 8
        const float* Wp = W_s + (size_t)k0 * H2_ + h;
        #pragma unroll 4
        for (int i = 0; i < 128; i += 4) {
            a0 = fmaf(sx[k0 + i    ], Wp[(size_t)(i    ) * H2_], a0);
            a1 = fmaf(sx[k0 + i + 1], Wp[(size_t)(i + 1) * H2_], a1);
            a2 = fmaf(sx[k0 + i + 2], Wp[(size_t)(i + 2) * H2_], a2);
            a3 = fmaf(sx[k0 + i + 3], Wp[(size_t)(i + 3) * H2_], a3);
        }
    }
    {
        const int j0 = kc * 32;                        // 256 / 8
        const float* Wp = W_z + (size_t)j0 * H2_ + h;
        #pragma unroll 4
        for (int i = 0; i < 32; i += 4) {
            a0 = fmaf(zx[j0 + i    ], Wp[(size_t)(i    ) * H2_], a0);
            a1 = fmaf(zx[j0 + i + 1], Wp[(size_t)(i + 1) * H2_], a1);
            a2 = fmaf(zx[j0 + i + 2], Wp[(size_t)(i + 2) * H2_], a2);
            a3 = fmaf(zx[j0 + i + 3], Wp[(size_t)(i + 3) * H2_], a3);
        }
    }
    const float acc = (a0 + a1) + (a2 + a3);

    __shared__ float part[8][32];
    part[kc][hl] = acc;
    __syncthreads();
    if (kc == 0) {
        float r = b_c[h];
        #pragma unroll
        for (int c = 0; c < 8; ++c) r += part[c][hl];
        combined[b * H2_ + h] = r;
    }
}

// Kernel 2: e[row] = sum_h tanh(enc[row][h] + cov[row]*W_c[h] + combined[b][h]) * v[h]
// Wave-per-8-rows: W_c/v/combined[b] hoisted into 48 VGPRs per thread ONCE,
// then 8 rows streamed (2-row pairs for load ILP). Loads per row = 4 enc
// float4 + 1 coverage scalar -- removes the 4x L1 traffic amplification of
// re-loading wc/v/cb per row.
// block = 256 (4 waves), each block covers 32 consecutive rows (same batch
// since 32 | 1024). grid = B*S/32 = 1024.
__global__ __launch_bounds__(256, 4) void et_kernel(
    const float* __restrict__ enc,       // [B, S, H2]
    const float* __restrict__ coverage,  // [B, S]
    const float* __restrict__ W_c,       // [H2]
    const float* __restrict__ v,         // [H2]
    const float* __restrict__ combined,  // [B, H2]
    float* __restrict__ e_out)           // [B, S]
{
    const int tid  = threadIdx.x;
    const int wv   = tid >> 6;
    const int lane = tid & 63;
    const int row0 = blockIdx.x * 32 + wv * 8;   // 8 rows per wave
    const int b    = row0 >> 10;                 // S = 1024

    const float4* com4 = (const float4*)(combined + (size_t)b * H2_);
    const float4* wc4  = (const float4*)W_c;
    const float4* v4   = (const float4*)v;

    // Hoisted per-wave invariants: 12 float4 = 48 VGPRs.
    float4 wc[4], vv[4], cb[4];
    #pragma unroll
    for (int i = 0; i < 4; ++i) {
        const int idx = lane + i * 64;
        wc[i] = wc4[idx];
        vv[i] = v4[idx];
        cb[i] = com4[idx];
    }

    // 8 rows, processed as 4 pairs; unroll 1 keeps ~2 rows of loads in
    // flight (controls VGPR pressure; TLP across 16 waves/CU hides latency).
    #pragma unroll 1
    for (int rp = 0; rp < 8; rp += 2) {
        const int ra = row0 + rp;
        const int rb = ra + 1;
        const float4* ea = (const float4*)enc + (size_t)ra * (H2_ / 4);
        const float4* eb = (const float4*)enc + (size_t)rb * (H2_ / 4);
        const float cva = coverage[ra];
        const float cvb = coverage[rb];

        float4 La[4], Lb[4];
        #pragma unroll
        for (int i = 0; i < 4; ++i) {
            La[i] = ea[lane + i * 64];
            Lb[i] = eb[lane + i * 64];
        }

        float aca = 0.0f, acb = 0.0f;
        #pragma unroll
        for (int i = 0; i < 4; ++i) {
            aca = fmaf(fast_tanh(fmaf(cva, wc[i].x, La[i].x + cb[i].x)), vv[i].x, aca);
            aca = fmaf(fast_tanh(fmaf(cva, wc[i].y, La[i].y + cb[i].y)), vv[i].y, aca);
            aca = fmaf(fast_tanh(fmaf(cva, wc[i].z, La[i].z + cb[i].z)), vv[i].z, aca);
            aca = fmaf(fast_tanh(fmaf(cva, wc[i].w, La[i].w + cb[i].w)), vv[i].w, aca);
            acb = fmaf(fast_tanh(fmaf(cvb, wc[i].x, Lb[i].x + cb[i].x)), vv[i].x, acb);
            acb = fmaf(fast_tanh(fmaf(cvb, wc[i].y, Lb[i].y + cb[i].y)), vv[i].y, acb);
            acb = fmaf(fast_tanh(fmaf(cvb, wc[i].z, Lb[i].z + cb[i].z)), vv[i].z, acb);
            acb = fmaf(fast_tanh(fmaf(cvb, wc[i].w, Lb[i].w + cb[i].w)), vv[i].w, acb);
        }

        #pragma unroll
        for (int off = 32; off > 0; off >>= 1) {
            aca += __shfl_xor(aca, off, 64);
            acb += __shfl_xor(acb, off, 64);
        }
        if (lane == 0) {
            e_out[ra] = aca;
            e_out[rb] = acb;
        }
    }
}

// Kernel 3: masked softmax over S per batch + next_coverage
// grid = B, block = 256 (4 elems per thread)
__global__ __launch_bounds__(256) void softmax_kernel(
    const float* __restrict__ e_in,      // [B, S]
    const int*   __restrict__ mask,      // [B, S]
    const float* __restrict__ coverage,  // [B, S]
    float* __restrict__ a_out,           // [B, S]
    float* __restrict__ cov_out)         // [B, S]
{
    const int b   = blockIdx.x;
    const int tid = threadIdx.x;

    float ev[4];
    #pragma unroll
    for (int i = 0; i < 4; ++i) {
        const int idx = b * S_ + tid * 4 + i;
        float e = e_in[idx];
        if (mask[idx] == 0) e = -INFINITY;
        ev[i] = e;
    }

    float m = fmaxf(fmaxf(ev[0], ev[1]), fmaxf(ev[2], ev[3]));
    #pragma unroll
    for (int off = 1; off < 64; off <<= 1)
        m = fmaxf(m, __shfl_xor(m, off, 64));

    __shared__ float red[4];
    if ((tid & 63) == 0) red[tid >> 6] = m;
    __syncthreads();
    m = fmaxf(fmaxf(red[0], red[1]), fmaxf(red[2], red[3]));

    float p[4];
    float lsum = 0.0f;
    #pragma unroll
    for (int i = 0; i < 4; ++i) {
        p[i] = __expf(ev[i] - m);
        lsum += p[i];
    }
    #pragma unroll
    for (int off = 1; off < 64; off <<= 1)
        lsum += __shfl_xor(lsum, off, 64);

    __syncthreads();  // everyone done reading red[] from max phase
    if ((tid & 63) == 0) red[tid >> 6] = lsum;
    __syncthreads();
    const float tot = red[0] + red[1] + red[2] + red[3];
    const float inv = 1.0f / tot;

    #pragma unroll
    for (int i = 0; i < 4; ++i) {
        const int idx = b * S_ + tid * 4 + i;
        const float a = p[i] * inv;
        a_out[idx]   = a;
        cov_out[idx] = coverage[idx] + a;
    }
}

extern "C" void kernel_launch(void* const* d_in, const int* in_sizes, int n_in,
                              void* d_out, int out_size, void* d_ws, size_t ws_size,
                              hipStream_t stream) {
    const float* enc      = (const float*)d_in[0];
    const int*   mask     = (const int*)  d_in[1];
    const float* s        = (const float*)d_in[2];
    const float* coverage = (const float*)d_in[3];
    const float* hz       = (const float*)d_in[4];
    const float* W_s      = (const float*)d_in[5];
    const float* W_c      = (const float*)d_in[6];
    const float* b_c      = (const float*)d_in[7];
    const float* W_z      = (const float*)d_in[8];
    const float* v        = (const float*)d_in[9];

    float* out_a   = (float*)d_out;            // [B, S]
    float* out_cov = out_a + B_ * S_;          // [B, S]

    float* combined = (float*)d_ws;            // [B, H2]
    float* e_ws     = combined + B_ * H2_;     // [B, S]

    combined_kernel<<<dim3(H2_ / 32, B_), 256, 0, stream>>>(s, hz, W_s, W_z, b_c, combined);
    et_kernel<<<(B_ * S_) / 32, 256, 0, stream>>>(enc, coverage, W_c, v, combined, e_ws);
    softmax_kernel<<<B_, 256, 0, stream>>>(e_ws, mask, coverage, out_a, out_cov);
}